// Round 8
// baseline (697.715 us; speedup 1.0000x reference)
//
#include <hip/hip_runtime.h>

#define NN 8192
#define STEPS 64
#define DECAYF 0.9f
#define THRESHF 1.0f
#define K_MAX 384            // padded-ELL row capacity (mean nnz ~257, max ~320)
#define KITER (K_MAX / 64)   // 6 unrolled gather iterations, branch-free

#define CBLOCKS 256          // one block per CU; regular launch (co-resident de facto)
#define CTHREADS 1024        // 16 waves: wave 0 = poller, waves 1..15 = compute
#define NWAVES 16
#define ROWS_PER_BLOCK 32

typedef unsigned long long u64;
typedef unsigned int u32;
typedef unsigned short u16;

// Relaxed agent-scope sc0+sc1 accesses: bypass L1/L2, coherent at L3.
// One aligned u64 = (step_tag<<32 | fire_bits): publish == barrier-arrive.
// PULL model (R7 post-mortem: push-scatter caused 138 MB HBM writeback;
// pull keeps the 4 KB mailbox L3-resident). Parity double-buffer (R5 fix).
__device__ __forceinline__ void pub_store(u64* p, u64 v) {
    __hip_atomic_store(p, v, __ATOMIC_RELAXED, __HIP_MEMORY_SCOPE_AGENT);
}
__device__ __forceinline__ u64 pub_load(const u64* p) {
    return __hip_atomic_load(p, __ATOMIC_RELAXED, __HIP_MEMORY_SCOPE_AGENT);
}

__global__ __launch_bounds__(CTHREADS) void spiking_all(
        const float* __restrict__ W,
        const float* __restrict__ f0,
        const float* __restrict__ v0,
        float* __restrict__ out,
        u64* __restrict__ fdata) {     // [2][CBLOCKS]
    __shared__ float lds_vals[ROWS_PER_BLOCK * K_MAX];   // 48 KB (zero-padded)
    __shared__ u16   lds_cols[ROWS_PER_BLOCK * K_MAX];   // 24 KB (zero-padded)
    __shared__ u32   lds_fbits[2][CBLOCKS];              // 2 KB, dbuf by parity
    __shared__ u32   lds_spike[NWAVES];
    __shared__ int   lds_flag;                           // monotonic: inputs ready
    __shared__ int   lds_cnt[STEPS];                     // per-step arrive counters

    const int tid  = threadIdx.x;
    const int wave = tid >> 6;
    const int lane = tid & 63;
    const int bid  = blockIdx.x;
    const u64 lmask = (1ull << lane) - 1ull;

    // ---- publish own f0 word FIRST (tag 1, slot 0): arrivals overlap the
    //      ~50 µs extraction phase everywhere. ----
    if (wave == 0) {
        float f = (lane < ROWS_PER_BLOCK) ? f0[bid * ROWS_PER_BLOCK + lane] : 0.0f;
        u64 m = __ballot(f != 0.0f);
        if (lane == 0)
            pub_store(&fdata[bid], (1ull << 32) | (u32)(m & 0xffffffffull));
    }

    // ---- extraction: 16 waves x 2 rows -> LDS ELL, padding zero-filled so the
    //      gather needs no count and no predication (pad: col=0, val=0.0). ----
    for (int rr = 0; rr < 2; ++rr) {
        const int lr  = wave * 2 + rr;
        const int row = bid * ROWS_PER_BLOCK + lr;
        float* ev = lds_vals + lr * K_MAX;
        u16*   ec = lds_cols + lr * K_MAX;
        for (int j = lane; j < K_MAX; j += 64) { ev[j] = 0.0f; ec[j] = 0; }
        const float4* wr4 = (const float4*)(W + (size_t)row * NN);
        int base = 0;
        for (int c4 = lane; c4 < NN / 4; c4 += 64) {
            float4 w = wr4[c4];
            const int col0 = c4 * 4;
            #pragma unroll
            for (int comp = 0; comp < 4; ++comp) {
                float val = (comp == 0) ? w.x : (comp == 1) ? w.y
                          : (comp == 2) ? w.z : w.w;
                u64 m = __ballot(val != 0.0f);
                if (val != 0.0f) {
                    int idx = base + __popcll(m & lmask);
                    if (idx < K_MAX) {               // statistically unreachable
                        ev[idx] = val;
                        ec[idx] = (u16)(col0 + comp);
                    }
                }
                base += __popcll(m);
            }
        }
    }
    if (tid < STEPS) lds_cnt[tid] = 0;
    if (tid == 0) lds_flag = 0;
    __syncthreads();   // one-time full barrier: ELL + control vars ready

    if (wave == 0) {
        // =================== POLLER (no global stores in loop) ===============
        for (int s = 0; s < STEPS; ++s) {
            const u64* slot = fdata + (size_t)(s & 1) * CBLOCKS;
            const u32 want = (u32)(s + 1);
            u64 w0, w1, w2, w3;
            for (;;) {
                w0 = pub_load(&slot[lane]);
                w1 = pub_load(&slot[lane + 64]);
                w2 = pub_load(&slot[lane + 128]);
                w3 = pub_load(&slot[lane + 192]);
                int ok = ((u32)(w0 >> 32) == want) & ((u32)(w1 >> 32) == want)
                       & ((u32)(w2 >> 32) == want) & ((u32)(w3 >> 32) == want);
                if (__all(ok)) break;
            }
            u32* fb = lds_fbits[s & 1];
            fb[lane]       = (u32)w0;
            fb[lane + 64]  = (u32)w1;
            fb[lane + 128] = (u32)w2;
            fb[lane + 192] = (u32)w3;
            if (lane == 0)
                __hip_atomic_store(&lds_flag, s + 1, __ATOMIC_RELEASE,
                                   __HIP_MEMORY_SCOPE_WORKGROUP);
        }
    } else {
        // =================== COMPUTE (waves 1..15, 32 rows) ==================
        // wave w owns rows w-1, w+14, and (w<=2) w+29.
        const int nr = (wave <= 2) ? 3 : 2;
        int lrs[3] = { wave - 1, wave + 14, wave + 29 };
        float vreg[3];
        for (int i = 0; i < nr; ++i)
            vreg[i] = v0[bid * ROWS_PER_BLOCK + lrs[i]];

        for (int s = 0; s < STEPS; ++s) {
            while (__hip_atomic_load(&lds_flag, __ATOMIC_ACQUIRE,
                                     __HIP_MEMORY_SCOPE_WORKGROUP) < s + 1) {}
            const u32* fb = lds_fbits[s & 1];
            float* orow = out + (size_t)s * NN + bid * ROWS_PER_BLOCK;
            u32 spikebits = 0;

            for (int i = 0; i < nr; ++i) {
                const int lr = lrs[i];
                const float* ev = lds_vals + lr * K_MAX;
                const u16*   ec = lds_cols + lr * K_MAX;
                double acc = 0.0;
                #pragma unroll
                for (int k = 0; k < KITER; ++k) {       // branch-free gather
                    const int j = lane + (k << 6);
                    u32 c   = (u32)ec[j];
                    float wv = ev[j];
                    u32 bit = (fb[c >> 5] >> (c & 31)) & 1u;
                    acc += bit ? (double)wv : 0.0;
                }
                #pragma unroll
                for (int off = 32; off >= 1; off >>= 1)
                    acc += __shfl_down(acc, off, 64);
                if (lane == 0) {
                    float u  = (float)acc;
                    float vv = __fadd_rn(__fmul_rn(DECAYF, vreg[i]), u);
                    int fire = (vv >= THRESHF);
                    vreg[i] = fire ? 0.0f : vv;
                    orow[lr] = fire ? 1.0f : 0.0f;      // L2 store, never drained
                    spikebits |= (u32)fire << lr;
                }
            }

            // arrive; 15th arriver assembles the 32-bit word and publishes
            int old = -1;
            if (lane == 0) {
                __hip_atomic_store(&lds_spike[wave], spikebits, __ATOMIC_RELAXED,
                                   __HIP_MEMORY_SCOPE_WORKGROUP);
                old = __hip_atomic_fetch_add(&lds_cnt[s], 1, __ATOMIC_ACQ_REL,
                                             __HIP_MEMORY_SCOPE_WORKGROUP);
            }
            old = __shfl(old, 0, 64);
            if (old == NWAVES - 2) {                     // 15th compute wave
                u32 b = (lane >= 1 && lane < NWAVES) ? lds_spike[lane] : 0u;
                #pragma unroll
                for (int off = 8; off >= 1; off >>= 1)
                    b |= __shfl_down(b, off, 64);
                if (lane == 0) {
                    u64 word = ((u64)(u32)(s + 2) << 32) | b;
                    pub_store(&fdata[(size_t)((s + 1) & 1) * CBLOCKS + bid], word);
                }
            }
        }
    }
}

extern "C" void kernel_launch(void* const* d_in, const int* in_sizes, int n_in,
                              void* d_out, int out_size, void* d_ws, size_t ws_size,
                              hipStream_t stream) {
    const float* W  = (const float*)d_in[0];
    const float* f0 = (const float*)d_in[1];
    const float* v0 = (const float*)d_in[2];
    float* out = (float*)d_out;

    u64* fdata = (u64*)d_ws;   // [2][256] u64 = 4 KB; 0xAA poison != any tag 1..65

    spiking_all<<<dim3(CBLOCKS), dim3(CTHREADS), 0, stream>>>(W, f0, v0, out, fdata);
}

// Round 9
// 663.347 us; speedup vs baseline: 1.0518x; 1.0518x over previous
//
#include <hip/hip_runtime.h>

#define NN 8192
#define STEPS 64
#define DECAYF 0.9f
#define THRESHF 1.0f
#define K_MAX 384            // padded-ELL row capacity (mean nnz ~257, max ~320)
#define KITER2 (K_MAX / 32)  // 12 gather iters at 32 lanes/row, branch-free

#define CBLOCKS 256          // one block per CU; regular launch
#define CTHREADS 1024        // 16 waves; wave 0 polls then computes like the rest
#define NWAVES 16
#define ROWS_PER_BLOCK 32    // 2 rows per wave, 32 lanes per row

typedef unsigned long long u64;
typedef unsigned int u32;
typedef unsigned short u16;

// Relaxed agent-scope sc0+sc1 accesses: bypass L1/L2, coherent at L3.
// One aligned u64 = (step_tag<<32 | fire_bits): publish == barrier-arrive.
// Pull model (R7: push-scatter caused HBM writeback), parity double-buffer
// (R5 fix). R6/R7/R8 A/B showed sync scheme is NOT the bottleneck -> this
// round attacks the per-step compute chain instead.
__device__ __forceinline__ void pub_store(u64* p, u64 v) {
    __hip_atomic_store(p, v, __ATOMIC_RELAXED, __HIP_MEMORY_SCOPE_AGENT);
}
__device__ __forceinline__ u64 pub_load(const u64* p) {
    return __hip_atomic_load(p, __ATOMIC_RELAXED, __HIP_MEMORY_SCOPE_AGENT);
}

__global__ __launch_bounds__(CTHREADS) void spiking_all(
        const float* __restrict__ W,
        const float* __restrict__ f0,
        const float* __restrict__ v0,
        float* __restrict__ out,
        u64* __restrict__ fdata) {     // [2][CBLOCKS]
    __shared__ u64 lds_pk[ROWS_PER_BLOCK * K_MAX];   // 96 KB: (col<<32)|f32bits
    __shared__ u32 lds_fbits[2][CBLOCKS];            // 2 KB, dbuf by parity
    __shared__ u32 lds_spike[NWAVES];
    __shared__ int lds_flag;                         // monotonic: inputs ready
    __shared__ int lds_cnt[STEPS];                   // per-step arrive counters

    const int tid  = threadIdx.x;
    const int wave = tid >> 6;
    const int lane = tid & 63;
    const int bid  = blockIdx.x;
    const u64 lmask = (1ull << lane) - 1ull;

    // ---- publish own f0 word FIRST (tag 1, slot 0): overlaps extraction ----
    if (wave == 0) {
        float f = (lane < ROWS_PER_BLOCK) ? f0[bid * ROWS_PER_BLOCK + lane] : 0.0f;
        u64 m = __ballot(f != 0.0f);
        if (lane == 0)
            pub_store(&fdata[bid], (1ull << 32) | (u32)(m & 0xffffffffull));
    }

    // ---- extraction: wave w compacts its own rows 2w, 2w+1 into packed LDS
    //      ELL (zero-padded: col=0,val=0 -> gather reads are harmless). ----
    for (int rr = 0; rr < 2; ++rr) {
        const int lr  = wave * 2 + rr;
        const int row = bid * ROWS_PER_BLOCK + lr;
        u64* pk = lds_pk + lr * K_MAX;
        for (int j = lane; j < K_MAX; j += 64) pk[j] = 0ull;
        const float4* wr4 = (const float4*)(W + (size_t)row * NN);
        int base = 0;
        for (int c4 = lane; c4 < NN / 4; c4 += 64) {
            float4 w = wr4[c4];
            const int col0 = c4 * 4;
            #pragma unroll
            for (int comp = 0; comp < 4; ++comp) {
                float val = (comp == 0) ? w.x : (comp == 1) ? w.y
                          : (comp == 2) ? w.z : w.w;
                u64 m = __ballot(val != 0.0f);
                if (val != 0.0f) {
                    int idx = base + __popcll(m & lmask);
                    if (idx < K_MAX)                 // statistically unreachable
                        pk[idx] = ((u64)(u32)(col0 + comp) << 32)
                                | (u64)__float_as_uint(val);
                }
                base += __popcll(m);
            }
        }
    }
    if (tid < STEPS) lds_cnt[tid] = 0;
    if (tid == 0) lds_flag = 0;

    // membrane potential: lanes 0..31 track row 2w, lanes 32..63 row 2w+1.
    // All 32 lanes of a half hold identical v (updates are deterministic).
    const int lr   = wave * 2 + (lane >> 5);         // this half-wave's row
    const int half = lane & 31;
    float vreg = v0[bid * ROWS_PER_BLOCK + lr];

    __syncthreads();   // one-time: ELL + control vars ready

    for (int s = 0; s < STEPS; ++s) {
        // ---- wave 0: poll mailbox, broadcast to LDS, release flag ----
        if (wave == 0) {
            const u64* slot = fdata + (size_t)(s & 1) * CBLOCKS;
            const u32 want = (u32)(s + 1);
            u64 w0, w1, w2, w3;
            for (;;) {
                w0 = pub_load(&slot[lane]);
                w1 = pub_load(&slot[lane + 64]);
                w2 = pub_load(&slot[lane + 128]);
                w3 = pub_load(&slot[lane + 192]);
                int ok = ((u32)(w0 >> 32) == want) & ((u32)(w1 >> 32) == want)
                       & ((u32)(w2 >> 32) == want) & ((u32)(w3 >> 32) == want);
                if (__all(ok)) break;
            }
            u32* fb = lds_fbits[s & 1];
            fb[lane]       = (u32)w0;
            fb[lane + 64]  = (u32)w1;
            fb[lane + 128] = (u32)w2;
            fb[lane + 192] = (u32)w3;
            if (lane == 0)
                __hip_atomic_store(&lds_flag, s + 1, __ATOMIC_RELEASE,
                                   __HIP_MEMORY_SCOPE_WORKGROUP);
        } else {
            while (__hip_atomic_load(&lds_flag, __ATOMIC_ACQUIRE,
                                     __HIP_MEMORY_SCOPE_WORKGROUP) < s + 1)
                __builtin_amdgcn_s_sleep(1);
        }

        const u32* fb = lds_fbits[s & 1];
        const u64* pk = lds_pk + lr * K_MAX;

        // ---- gather: 32 lanes per row, packed b64 + fb-bit test ----
        double acc = 0.0;
        #pragma unroll
        for (int k = 0; k < KITER2; ++k) {
            const int j = half + (k << 5);
            u64 p   = pk[j];
            u32 c   = (u32)(p >> 32);
            float v = __uint_as_float((u32)p);
            u32 bit = (fb[c >> 5] >> (c & 31)) & 1u;
            acc += bit ? (double)v : 0.0;
        }
        // butterfly over the 32-lane half: every lane ends with its row's sum
        #pragma unroll
        for (int m = 16; m >= 1; m >>= 1)
            acc += __shfl_xor(acc, m, 64);

        // ---- LIF update (computed redundantly on all lanes, consistent) ----
        float u  = (float)acc;
        float vv = __fadd_rn(__fmul_rn(DECAYF, vreg), u);
        int fire = (vv >= THRESHF);
        vreg = fire ? 0.0f : vv;
        if (half == 0)
            out[(size_t)s * NN + bid * ROWS_PER_BLOCK + lr] = fire ? 1.0f : 0.0f;

        // bal: low 32 bits replicate row0's fire, high 32 replicate row1's
        u64 bal = __ballot(fire);
        u32 bits2 = (u32)(bal & 1ull) | (u32)((bal >> 31) & 2ull);

        // ---- arrive; 16th arriver assembles 32 bits and publishes tag s+2 ----
        int old = -1;
        if (lane == 0) {
            __hip_atomic_store(&lds_spike[wave], bits2, __ATOMIC_RELAXED,
                               __HIP_MEMORY_SCOPE_WORKGROUP);
            old = __hip_atomic_fetch_add(&lds_cnt[s], 1, __ATOMIC_ACQ_REL,
                                         __HIP_MEMORY_SCOPE_WORKGROUP);
        }
        old = __shfl(old, 0, 64);
        if (old == NWAVES - 1) {                     // last wave to finish
            u32 b = (lane < NWAVES) ? (lds_spike[lane] << (2 * lane)) : 0u;
            #pragma unroll
            for (int off = 8; off >= 1; off >>= 1)
                b |= __shfl_down(b, off, 64);
            if (lane == 0) {
                u64 word = ((u64)(u32)(s + 2) << 32) | b;
                pub_store(&fdata[(size_t)((s + 1) & 1) * CBLOCKS + bid], word);
            }
        }
    }
}

extern "C" void kernel_launch(void* const* d_in, const int* in_sizes, int n_in,
                              void* d_out, int out_size, void* d_ws, size_t ws_size,
                              hipStream_t stream) {
    const float* W  = (const float*)d_in[0];
    const float* f0 = (const float*)d_in[1];
    const float* v0 = (const float*)d_in[2];
    float* out = (float*)d_out;

    u64* fdata = (u64*)d_ws;   // [2][256] u64 = 4 KB; 0xAA poison != any tag 1..65

    spiking_all<<<dim3(CBLOCKS), dim3(CTHREADS), 0, stream>>>(W, f0, v0, out, fdata);
}

// Round 10
// 607.051 us; speedup vs baseline: 1.1494x; 1.0927x over previous
//
#include <hip/hip_runtime.h>

#define NN 8192
#define STEPS 64
#define DECAYF 0.9f
#define THRESHF 1.0f
#define K_MAX 384            // padded-ELL row capacity (mean nnz ~257, max ~320)
#define KITER 24             // 384 / 16 lanes per row

#define CBLOCKS 256          // one block per CU; regular launch
#define STHREADS 576         // 9 waves: wave 0 = poller/publisher, 1..8 compute

typedef unsigned long long u64;
typedef unsigned int u32;

// Relaxed agent-scope sc0+sc1 accesses: bypass L1/L2, coherent at L3.
// One aligned u64 = (step_tag<<32 | fire_bits): publish == barrier-arrive.
// Pull model + parity double-buffer (R5/R7 lessons). R6/7/8 A/B: sync scheme
// itself is not the bottleneck; R9: serial chain length is. This round:
// ELL in VGPRs, 9 waves, tagged-word fan-in (no atomic RMW chain).
__device__ __forceinline__ void pub_store(u64* p, u64 v) {
    __hip_atomic_store(p, v, __ATOMIC_RELAXED, __HIP_MEMORY_SCOPE_AGENT);
}
__device__ __forceinline__ u64 pub_load(const u64* p) {
    return __hip_atomic_load(p, __ATOMIC_RELAXED, __HIP_MEMORY_SCOPE_AGENT);
}

// ---------------------------------------------------------------------------
// Dispatch 1: W -> packed global ELL (zero-padded). One wave per row.
// Separate dispatch => rocprof reports extraction vs steps independently.
// ---------------------------------------------------------------------------
__global__ __launch_bounds__(256) void extract_ell(
        const float* __restrict__ W,
        u64* __restrict__ pk) {          // [NN][K_MAX] = (col<<32)|f32bits
    const int wave = threadIdx.x >> 6;
    const int lane = threadIdx.x & 63;
    const int row  = blockIdx.x * 4 + wave;
    const float4* wr4 = (const float4*)(W + (size_t)row * NN);
    u64* pr = pk + (size_t)row * K_MAX;
    const u64 lmask = (1ull << lane) - 1ull;

    int base = 0;
    for (int c4 = lane; c4 < NN / 4; c4 += 64) {
        float4 w = wr4[c4];
        const int col0 = c4 * 4;
        #pragma unroll
        for (int comp = 0; comp < 4; ++comp) {
            float val = (comp == 0) ? w.x : (comp == 1) ? w.y
                      : (comp == 2) ? w.z : w.w;
            u64 m = __ballot(val != 0.0f);
            if (val != 0.0f) {
                int idx = base + __popcll(m & lmask);
                if (idx < K_MAX)                 // statistically unreachable
                    pr[idx] = ((u64)(u32)(col0 + comp) << 32)
                            | (u64)__float_as_uint(val);
            }
            base += __popcll(m);
        }
    }
    // zero-fill the tail AFTER compaction (no same-address write ordering issue)
    const int cap = (base < K_MAX) ? base : K_MAX;
    for (int j = cap + lane; j < K_MAX; j += 64) pr[j] = 0ull;
}

// ---------------------------------------------------------------------------
// Dispatch 2: persistent step kernel. 9 waves. ELL lives in VGPRs.
// ---------------------------------------------------------------------------
__global__ __launch_bounds__(STHREADS) void spiking_steps(
        const u64* __restrict__ pk,
        const float* __restrict__ f0,
        const float* __restrict__ v0,
        float* __restrict__ out,
        u64* __restrict__ fdata) {       // [2][CBLOCKS]
    __shared__ u32 lds_fbits[2][CBLOCKS];    // 2 KB, dbuf by parity
    __shared__ u32 lds_spike[16];            // tagged: (step<<8)|bits4
    __shared__ int lds_flag;                 // monotonic: inputs ready

    const int tid  = threadIdx.x;
    const int wave = tid >> 6;
    const int lane = tid & 63;
    const int bid  = blockIdx.x;

    if (tid < 16) lds_spike[tid] = 0;
    if (tid == 0) lds_flag = 0;

    // publish own f0 word (tag 1, slot 0) ASAP
    if (wave == 0) {
        float f = (lane < 32) ? f0[bid * 32 + lane] : 0.0f;
        u64 m = __ballot(f != 0.0f);
        if (lane == 0)
            pub_store(&fdata[bid], (1ull << 32) | (u32)(m & 0xffffffffull));
    }
    __syncthreads();   // only barrier in the kernel (control-var init)

    if (wave == 0) {
        // ================= POLLER + PUBLISHER =================
        for (int s = 0; s < STEPS; ++s) {
            const u64* slot = fdata + (size_t)(s & 1) * CBLOCKS;
            const u32 want = (u32)(s + 1);
            u64 w0, w1, w2, w3;
            for (;;) {
                w0 = pub_load(&slot[lane]);
                w1 = pub_load(&slot[lane + 64]);
                w2 = pub_load(&slot[lane + 128]);
                w3 = pub_load(&slot[lane + 192]);
                int ok = ((u32)(w0 >> 32) == want) & ((u32)(w1 >> 32) == want)
                       & ((u32)(w2 >> 32) == want) & ((u32)(w3 >> 32) == want);
                if (__all(ok)) break;
            }
            u32* fb = lds_fbits[s & 1];
            fb[lane]       = (u32)w0;
            fb[lane + 64]  = (u32)w1;
            fb[lane + 128] = (u32)w2;
            fb[lane + 192] = (u32)w3;
            if (lane == 0)
                __hip_atomic_store(&lds_flag, s + 1, __ATOMIC_RELEASE,
                                   __HIP_MEMORY_SCOPE_WORKGROUP);

            // collect the 8 tagged spike words (parallel spin, no RMW chain)
            u32 myw;
            for (;;) {
                myw = (lane < 8)
                    ? __hip_atomic_load(&lds_spike[1 + lane], __ATOMIC_RELAXED,
                                        __HIP_MEMORY_SCOPE_WORKGROUP)
                    : (want << 8);
                if (__all((myw >> 8) == want)) break;
            }
            u32 bits = (lane < 8) ? ((myw & 0xFu) << (lane * 4)) : 0u;
            bits |= __shfl_xor(bits, 1, 64);
            bits |= __shfl_xor(bits, 2, 64);
            bits |= __shfl_xor(bits, 4, 64);
            if (lane == 0)
                pub_store(&fdata[(size_t)((s + 1) & 1) * CBLOCKS + bid],
                          ((u64)(u32)(s + 2) << 32) | bits);
        }
    } else {
        // ================= COMPUTE (waves 1..8, 4 rows each) =================
        const int g    = wave - 1;               // 0..7
        const int rloc = g * 4 + (lane >> 4);    // local row 0..31
        const int row  = bid * 32 + rloc;
        const int l16  = lane & 15;

        // one-time: load this lane's 24 ELL elements into registers
        u32 ecol[KITER]; float eval[KITER];
        const u64* pr = pk + (size_t)row * K_MAX;
        #pragma unroll
        for (int k = 0; k < KITER; ++k) {
            u64 p = pr[l16 + 16 * k];
            ecol[k] = (u32)(p >> 32);
            eval[k] = __uint_as_float((u32)p);
        }
        float vreg = v0[row];                    // identical across the 16 lanes

        for (int s = 0; s < STEPS; ++s) {
            while (__hip_atomic_load(&lds_flag, __ATOMIC_ACQUIRE,
                                     __HIP_MEMORY_SCOPE_WORKGROUP) < s + 1)
                __builtin_amdgcn_s_sleep(2);     // keep LDS pipe clear for poller
            const u32* fb = lds_fbits[s & 1];

            double acc = 0.0;
            #pragma unroll
            for (int k = 0; k < KITER; ++k) {
                u32 c = ecol[k];
                u32 w = fb[c >> 5];
                float sv = ((w >> (c & 31)) & 1u) ? eval[k] : 0.0f;
                acc += (double)sv;               // exact: zeros are no-ops
            }
            #pragma unroll
            for (int m = 8; m >= 1; m >>= 1)     // 16-lane butterfly
                acc += __shfl_xor(acc, m, 64);

            float u  = (float)acc;
            float vv = __fadd_rn(__fmul_rn(DECAYF, vreg), u);
            int fire = (vv >= THRESHF);
            vreg = fire ? 0.0f : vv;
            if (l16 == 0)
                out[(size_t)s * NN + row] = fire ? 1.0f : 0.0f;

            u64 bal = __ballot(fire);            // uniform within 16-lane groups
            if (lane == 0) {
                u32 bits4 = ((u32)(bal       ) & 1u)
                          | (((u32)(bal >> 16) & 1u) << 1)
                          | (((u32)(bal >> 32) & 1u) << 2)
                          | (((u32)(bal >> 48) & 1u) << 3);
                __hip_atomic_store(&lds_spike[1 + g],
                                   ((u32)(s + 1) << 8) | bits4,
                                   __ATOMIC_RELAXED, __HIP_MEMORY_SCOPE_WORKGROUP);
            }
        }
    }
}

extern "C" void kernel_launch(void* const* d_in, const int* in_sizes, int n_in,
                              void* d_out, int out_size, void* d_ws, size_t ws_size,
                              hipStream_t stream) {
    const float* W  = (const float*)d_in[0];
    const float* f0 = (const float*)d_in[1];
    const float* v0 = (const float*)d_in[2];
    float* out = (float*)d_out;

    // workspace: packed ELL (25.2 MB) | mailbox (4 KB)
    u64* pk    = (u64*)d_ws;
    u64* fdata = pk + (size_t)NN * K_MAX;   // 0xAA poison != any tag 1..66

    extract_ell<<<dim3(NN / 4), dim3(256), 0, stream>>>(W, pk);
    spiking_steps<<<dim3(CBLOCKS), dim3(STHREADS), 0, stream>>>(
        pk, f0, v0, out, fdata);
}